// Round 6
// baseline (891.887 us; speedup 1.0000x reference)
//
#include <hip/hip_runtime.h>
#include <cstdint>

#define K_CODES 8192
#define D_DIM   256
#define N_TOT   16384
#define HW      1024

#define BN 128
#define BK 128
#define DC 32
#define KSPLIT 8
#define KT_PER (K_CODES / KSPLIT / BK)   // 8 k-tiles per block

// ---------------------------------------------------------------------------
// numpy pairwise_sum replication for sum of 256 f32 squares.
// numpy: np.sum(x*x) with n=256 -> pairwise split 128+128; each 128-block:
// r[j] = a[j]; for i=8..120 step 8: r[j] += a[i+j];
// block = ((r0+r1)+(r2+r3)) + ((r4+r5)+(r6+r7)); total = blk0 + blk1.
// Squares are a materialized array in numpy (rounded before summing), so
// fp contract(off) to forbid fma fusion of mul into add.
// ---------------------------------------------------------------------------
__device__ __forceinline__ float np_sq_norm_256(const float* __restrict__ p,
                                                const int stride) {
    #pragma clang fp contract(off)
    float blk[2];
    #pragma unroll
    for (int b = 0; b < 2; ++b) {
        const float* q = p + b * 128 * stride;
        float r[8];
        #pragma unroll
        for (int j = 0; j < 8; ++j) { const float v = q[j * stride]; r[j] = v * v; }
        for (int i = 8; i < 128; i += 8) {
            #pragma unroll
            for (int j = 0; j < 8; ++j) {
                const float v = q[(i + j) * stride];
                r[j] += v * v;
            }
        }
        blk[b] = ((r[0] + r[1]) + (r[2] + r[3])) + ((r[4] + r[5]) + (r[6] + r[7]));
    }
    return blk[0] + blk[1];
}

// ---------------------------------------------------------------- cn2 ------
// one thread per code row (contiguous stride-1)
__global__ __launch_bounds__(256) void cn2_kernel(const float* __restrict__ emb,
                                                  float* __restrict__ cn2) {
    const int row = blockIdx.x * 256 + threadIdx.x;
    cn2[row] = np_sq_norm_256(emb + (size_t)row * D_DIM, 1);
}

// ---------------------------------------------------------------- zn2 ------
// one thread per latent vector n; z is NCHW so channel stride = HW (coalesced
// across lanes: consecutive n = consecutive hw)
__global__ __launch_bounds__(256) void zn2_kernel(const float* __restrict__ z_e,
                                                  float* __restrict__ zn2) {
    const int n = blockIdx.x * 256 + threadIdx.x;
    const int b = n >> 10, hw = n & (HW - 1);
    zn2[n] = np_sq_norm_256(z_e + (size_t)b * (D_DIM * HW) + hw, HW);
}

// ------------------------------------------------------------ main GEMM ----
// grid: (N_TOT/BN, KSPLIT), block: 256 threads.
// wave w = tid/64 -> (wr = w>>1, wc = w&1); lane -> (lr = lane>>3, lc = lane&7)
// thread output tile: n = nb + wr*64 + lr*8 + m (m=0..7)
//                     k = kk + wc*64 + lc*8 + q (q=0..7)
// Distance replicates numpy f32: d = fl( fl(zn2[n] + cn2[k]) - 2*g[n,k] )
__global__ __launch_bounds__(256, 4) void vq_main_kernel(
        const float* __restrict__ z_e, const float* __restrict__ emb,
        const float* __restrict__ cn2, const float* __restrict__ zn2,
        float* __restrict__ pvals, int* __restrict__ pidx) {
    __shared__ float zs[DC][BN];        // 16 KB, [d][n]
    __shared__ float cs[DC][BK + 4];    // 16.9 KB, [d][k], pad keeps 16B row align

    const int tid = threadIdx.x;
    const int w = tid >> 6;
    const int lane = tid & 63;
    const int wr = w >> 1, wc = w & 1;
    const int lr = lane >> 3, lc = lane & 7;

    const int nb = blockIdx.x * BN;
    const int ks = blockIdx.y;
    const int k0 = ks * (K_CODES / KSPLIT);

    const int b = nb >> 10;             // 128 | 1024, so one batch image per block
    const int hw0 = nb & (HW - 1);
    const float* zbase = z_e + (size_t)b * (D_DIM * HW) + hw0;

    const int zn0 = wr * 64 + lr * 8;
    const int ck0 = wc * 64 + lc * 8;

    // this thread's 8 row norms (exact numpy zn2 values)
    const float4 zna = *reinterpret_cast<const float4*>(zn2 + nb + zn0);
    const float4 znb = *reinterpret_cast<const float4*>(zn2 + nb + zn0 + 4);
    const float znv[8] = {zna.x, zna.y, zna.z, zna.w, znb.x, znb.y, znb.z, znb.w};

    float best[8];
    int bi[8];
    #pragma unroll
    for (int m = 0; m < 8; ++m) { best[m] = 3.4e38f; bi[m] = 0; }

    for (int kt = 0; kt < KT_PER; ++kt) {
        const int kk = k0 + kt * BK;
        float acc[8][8];
        #pragma unroll
        for (int m = 0; m < 8; ++m)
            #pragma unroll
            for (int q = 0; q < 8; ++q) acc[m][q] = 0.f;

        for (int dc = 0; dc < D_DIM; dc += DC) {
            __syncthreads();
            // stage z chunk: DC x BN (coalesced global, contiguous LDS writes)
            #pragma unroll
            for (int i = 0; i < 4; ++i) {
                const int fl = i * 256 + tid;       // 0..1023 float4 index
                const int d = fl >> 5;              // 32 float4 per d-row
                const int j4 = (fl & 31) << 2;
                *reinterpret_cast<float4*>(&zs[d][j4]) =
                    *reinterpret_cast<const float4*>(zbase + (size_t)(dc + d) * HW + j4);
            }
            // stage codes transposed: cs[d][k_local]
            #pragma unroll
            for (int i = 0; i < 4; ++i) {
                const int fl = i * 256 + tid;
                const int kl = fl >> 3;             // 8 float4 per code row chunk
                const int d4 = (fl & 7) << 2;
                const float4 v = *reinterpret_cast<const float4*>(
                    emb + (size_t)(kk + kl) * D_DIM + dc + d4);
                cs[d4 + 0][kl] = v.x;
                cs[d4 + 1][kl] = v.y;
                cs[d4 + 2][kl] = v.z;
                cs[d4 + 3][kl] = v.w;
            }
            __syncthreads();
            #pragma unroll 4
            for (int d = 0; d < DC; ++d) {
                const float4 za = *reinterpret_cast<const float4*>(&zs[d][zn0]);
                const float4 zb = *reinterpret_cast<const float4*>(&zs[d][zn0 + 4]);
                const float4 ca = *reinterpret_cast<const float4*>(&cs[d][ck0]);
                const float4 cb = *reinterpret_cast<const float4*>(&cs[d][ck0 + 4]);
                const float zf[8] = {za.x, za.y, za.z, za.w, zb.x, zb.y, zb.z, zb.w};
                const float cf[8] = {ca.x, ca.y, ca.z, ca.w, cb.x, cb.y, cb.z, cb.w};
                #pragma unroll
                for (int m = 0; m < 8; ++m)
                    #pragma unroll
                    for (int q = 0; q < 8; ++q)
                        acc[m][q] = fmaf(zf[m], cf[q], acc[m][q]);
            }
        }
        // d = fl( fl(zn2 + cn2) - 2*g ): matches numpy's rounding exactly
        // (2*g is exact; fmaf(-2,acc,A) == round(A - 2*acc), one rounding).
        const int kb = kk + ck0;
        const float4 cna = *reinterpret_cast<const float4*>(cn2 + kb);
        const float4 cnb = *reinterpret_cast<const float4*>(cn2 + kb + 4);
        const float cn[8] = {cna.x, cna.y, cna.z, cna.w, cnb.x, cnb.y, cnb.z, cnb.w};
        #pragma unroll
        for (int m = 0; m < 8; ++m) {
            #pragma unroll
            for (int q = 0; q < 8; ++q) {
                const float A = znv[m] + cn[q];              // fl32, no contraction risk
                const float v = fmaf(-2.f, acc[m][q], A);    // fl32(A - 2g)
                if (v < best[m]) { best[m] = v; bi[m] = kb + q; }
            }
        }
    }

    // reduce across lc (8 lanes, shuffle), then across wc (2 waves, via LDS)
    __syncthreads();
    float* redv = reinterpret_cast<float*>(&zs[0][0]);   // 256 floats
    int* redi = reinterpret_cast<int*>(&zs[8][0]);       // 256 ints (disjoint)
    #pragma unroll
    for (int m = 0; m < 8; ++m) {
        float v = best[m]; int idx = bi[m];
        #pragma unroll
        for (int s = 1; s < 8; s <<= 1) {
            const float ov = __shfl_xor(v, s, 64);
            const int oi = __shfl_xor(idx, s, 64);
            if (ov < v || (ov == v && oi < idx)) { v = ov; idx = oi; }
        }
        if (lc == 0) {
            redv[w * 64 + lr * 8 + m] = v;
            redi[w * 64 + lr * 8 + m] = idx;
        }
    }
    __syncthreads();
    if (tid < 128) {
        const int wr2 = tid >> 6, j = tid & 63;
        const float v0 = redv[(wr2 * 2) * 64 + j];
        const float v1 = redv[(wr2 * 2 + 1) * 64 + j];
        const int i0 = redi[(wr2 * 2) * 64 + j];
        const int i1 = redi[(wr2 * 2 + 1) * 64 + j];
        const bool t = (v1 < v0) || (v1 == v0 && i1 < i0);
        const int n = nb + wr2 * 64 + j;
        pvals[(size_t)n * KSPLIT + ks] = t ? v1 : v0;
        pidx[(size_t)n * KSPLIT + ks] = t ? i1 : i0;
    }
}

// ------------------------------------------------------- ksplit reduce ----
__global__ __launch_bounds__(256) void reduce_kernel(const float* __restrict__ pvals,
                                                     const int* __restrict__ pidx,
                                                     float* __restrict__ fidx) {
    const int n = blockIdx.x * 256 + threadIdx.x;
    float bv = 3.4e38f; int bidx = 0;
    #pragma unroll
    for (int s = 0; s < KSPLIT; ++s) {
        const float v = pvals[(size_t)n * KSPLIT + s];
        const int i = pidx[(size_t)n * KSPLIT + s];
        if (v < bv || (v == bv && i < bidx)) { bv = v; bidx = i; }
    }
    fidx[n] = (float)bidx;
}

// ------------------------------------------------------------- gather -----
__global__ __launch_bounds__(256) void gather_kernel(const float* __restrict__ emb,
                                                     const float* __restrict__ fidx,
                                                     float* __restrict__ zq) {
    const int tid = threadIdx.x;
    const int nb = blockIdx.x * 64;
    const int nl = tid & 63;
    const int dq = tid >> 6;            // 0..3
    const int b = nb >> 10, hw0 = nb & (HW - 1);
    const int k = (int)fidx[nb + nl];
    const float* er = emb + (size_t)k * D_DIM;
    float* ob = zq + (size_t)b * (D_DIM * HW) + hw0 + nl;
    #pragma unroll 8
    for (int dd = 0; dd < D_DIM; dd += 4) {
        const int d = dd + dq;
        ob[(size_t)d * HW] = er[d];
    }
}

// ------------------------------------------------------------- launch -----
extern "C" void kernel_launch(void* const* d_in, const int* in_sizes, int n_in,
                              void* d_out, int out_size, void* d_ws, size_t ws_size,
                              hipStream_t stream) {
    const float* z_e = (const float*)d_in[0];   // [16,256,32,32]
    const float* emb = (const float*)d_in[1];   // [8192,256]
    float* out = (float*)d_out;
    float* out_inp = out;                        // 4194304 floats
    float* out_zq  = out + 4194304;              // 4194304 floats
    float* out_idx = out + 8388608;              // 16384 floats

    // scratch carved from the z_q output region (gather overwrites it last)
    float* cn2   = out_zq;                               // 8192 floats
    float* pvals = out_zq + 8192;                        // 131072 floats
    int*   pidx  = (int*)(out_zq + 8192 + N_TOT * KSPLIT); // 131072 ints
    float* zn2   = out_zq + 8192 + 2 * N_TOT * KSPLIT;   // 16384 floats

    hipMemcpyAsync(out_inp, z_e, (size_t)N_TOT * D_DIM * sizeof(float),
                   hipMemcpyDeviceToDevice, stream);
    cn2_kernel<<<K_CODES / 256, 256, 0, stream>>>(emb, cn2);
    zn2_kernel<<<N_TOT / 256, 256, 0, stream>>>(z_e, zn2);
    vq_main_kernel<<<dim3(N_TOT / BN, KSPLIT), 256, 0, stream>>>(
        z_e, emb, cn2, zn2, pvals, pidx);
    reduce_kernel<<<N_TOT / 256, 256, 0, stream>>>(pvals, pidx, out_idx);
    gather_kernel<<<N_TOT / 64, 256, 0, stream>>>(emb, out_idx, out_zq);
}

// Round 7
// 394.781 us; speedup vs baseline: 2.2592x; 2.2592x over previous
//
#include <hip/hip_runtime.h>
#include <cstdint>

#define K_CODES 8192
#define D_DIM   256
#define N_TOT   16384
#define HW      1024
#define KSPLIT  8
#define BN      128
#define BK      128
#define KT_PER  (K_CODES / KSPLIT / BK)   // 8 k-tiles per block

typedef _Float16 f16;
typedef _Float16 f16x8 __attribute__((ext_vector_type(8)));
typedef float    f32x4 __attribute__((ext_vector_type(4)));

// ---------------------------------------------------------------------------
// numpy pairwise_sum replication for sum of 256 f32 squares (verified R6).
// ---------------------------------------------------------------------------
__device__ __forceinline__ float np_sq_norm_256(const float* __restrict__ p,
                                                const int stride) {
    #pragma clang fp contract(off)
    float blk[2];
    #pragma unroll
    for (int b = 0; b < 2; ++b) {
        const float* q = p + b * 128 * stride;
        float r[8];
        #pragma unroll
        for (int j = 0; j < 8; ++j) { const float v = q[j * stride]; r[j] = v * v; }
        for (int i = 8; i < 128; i += 8) {
            #pragma unroll
            for (int j = 0; j < 8; ++j) {
                const float v = q[(i + j) * stride];
                r[j] += v * v;
            }
        }
        blk[b] = ((r[0] + r[1]) + (r[2] + r[3])) + ((r[4] + r[5]) + (r[6] + r[7]));
    }
    return blk[0] + blk[1];
}

__global__ __launch_bounds__(256) void cn2_kernel(const float* __restrict__ emb,
                                                  float* __restrict__ cn2) {
    const int row = blockIdx.x * 256 + threadIdx.x;
    cn2[row] = np_sq_norm_256(emb + (size_t)row * D_DIM, 1);
}

__global__ __launch_bounds__(256) void zn2_kernel(const float* __restrict__ z_e,
                                                  float* __restrict__ zn2) {
    const int n = blockIdx.x * 256 + threadIdx.x;
    const int b = n >> 10, hw = n & (HW - 1);
    zn2[n] = np_sq_norm_256(z_e + (size_t)b * (D_DIM * HW) + hw, HW);
}

// ---------------------------------------------------------------------------
// f16 2-term splits. z = zh + zl/2048 (exact to ~2^-24 rel).
// c pre-scaled by 4096: c*4096 = ch + cl/2048. Scaled lo-terms stay f16-normal.
// z3/c3 row layout: [row][512] f16 = 256 hi | 256 lo.
// ---------------------------------------------------------------------------
__global__ __launch_bounds__(256) void split_z_kernel(const float* __restrict__ z_e,
                                                      f16* __restrict__ z3) {
    const int n = blockIdx.x * 256 + threadIdx.x;
    const int b = n >> 10, hw = n & (HW - 1);
    const float* p = z_e + (size_t)b * (D_DIM * HW) + hw;
    f16* o = z3 + (size_t)n * 512;
    for (int d = 0; d < 256; ++d) {
        const float v = p[(size_t)d * HW];
        const f16 h = (f16)v;
        const f16 lo = (f16)((v - (float)h) * 2048.0f);
        o[d] = h; o[256 + d] = lo;
    }
}

__global__ __launch_bounds__(256) void split_c_kernel(const float* __restrict__ emb,
                                                      f16* __restrict__ c3) {
    const int k = blockIdx.x * 256 + threadIdx.x;
    const float* p = emb + (size_t)k * D_DIM;
    f16* o = c3 + (size_t)k * 512;
    for (int d = 0; d < 256; ++d) {
        const float v = p[d] * 4096.0f;
        const f16 h = (f16)v;
        const f16 lo = (f16)((v - (float)h) * 2048.0f);
        o[d] = h; o[256 + d] = lo;
    }
}

// ---------------------------------------------------------------------------
// async global->LDS, 16B per lane (dest = lds_base + lane*16, linear)
// ---------------------------------------------------------------------------
__device__ __forceinline__ void gll16(const void* g, void* l) {
    __builtin_amdgcn_global_load_lds(
        (const __attribute__((address_space(1))) unsigned int*)g,
        (__attribute__((address_space(3))) unsigned int*)l, 16, 0, 0);
}

// ---------------------------------------------------------------------------
// MFMA main kernel. grid (KSPLIT, N_TOT/BN) -> XCD = bid%8 = blockIdx.x = ks,
// so each XCD's c-slice (1 MB) is L2-resident.
// Block: 256 thr = 4 waves, wave (wr,wc) owns 64n x 64k; frags 4x4 of 16x16x32.
// LDS per buf: 4 tiles (zh,zl,ch,cl) of [128 rows][4 x 16B d-blocks], 8 KB each,
// 16B-block swizzled: phys_db = log_db ^ ((row>>1)&3)  (bijective, uniform banks).
// Staging pre-applies the inverse swizzle on the *global* source per lane so
// global_load_lds writes linearly (G21: both-sides-or-neither).
// ---------------------------------------------------------------------------
__global__ __launch_bounds__(256, 2) void vq_mfma_kernel(
        const f16* __restrict__ z3, const f16* __restrict__ c3,
        const float* __restrict__ zn2, const float* __restrict__ cn2,
        float* __restrict__ pvals, int* __restrict__ pidx) {
    __shared__ __align__(16) char lds[2 * 32768];

    const int tid = threadIdx.x;
    const int w = tid >> 6, l = tid & 63;
    const int wr = w >> 1, wc = w & 1;
    const int g = l >> 4, li = l & 15;
    const int ks = blockIdx.x;
    const int nb = blockIdx.y * BN;
    const int kbase = ks * (K_CODES / KSPLIT);

    // LDS read offsets (bytes within a tile). A rows: n-local; B rows: k-local.
    const int swz = (li >> 1) & 3;
    const int dbp = ((g ^ swz) << 4);
    int offA[4], offB[4];
    #pragma unroll
    for (int f = 0; f < 4; ++f) {
        offA[f] = ((wr * 64 + f * 16 + li) << 6) + dbp;
        offB[f] = ((wc * 64 + f * 16 + li) << 6) + dbp;
    }

    // staging lane roles: lane j fills LDS slot (row j>>2, phys db j&3) of its
    // wave's chunk -> source logical db = (j&3) ^ ((j>>3)&3).
    const int srow = l >> 2;
    const int sdb = (l & 3) ^ ((l >> 3) & 3);
    const int s_half = w & 1;                       // 0 = hi plane, 1 = lo plane
    const f16* ssrc = (w < 2) ? z3 : c3;
    char* const sldst = lds;                        // + buf*32768 + w*8192 + g16*1024

    // preload zn2 (C/D row = 4*(l>>4)+reg within each fn block) — numpy-exact
    float zn[16];
    #pragma unroll
    for (int fn = 0; fn < 4; ++fn)
        #pragma unroll
        for (int r = 0; r < 4; ++r)
            zn[fn * 4 + r] = zn2[nb + wr * 64 + fn * 16 + 4 * g + r];

    float best[16]; int bi[16];
    #pragma unroll
    for (int i = 0; i < 16; ++i) { best[i] = 3.4e38f; bi[i] = 0; }

    f32x4 acc1[4][4], acc2[4][4];
    #pragma unroll
    for (int a = 0; a < 4; ++a)
        #pragma unroll
        for (int b2 = 0; b2 < 4; ++b2) {
            acc1[a][b2] = f32x4{0.f, 0.f, 0.f, 0.f};
            acc2[a][b2] = f32x4{0.f, 0.f, 0.f, 0.f};
        }

    #define STAGE(BUF, IT) do {                                                  \
        const int kt_ = (IT) >> 3, dc_ = (IT) & 7;                               \
        const int rb_ = (w < 2) ? nb : (kbase + kt_ * BK);                       \
        char* ld_ = sldst + (BUF) * 32768 + w * 8192;                            \
        _Pragma("unroll")                                                        \
        for (int g16 = 0; g16 < 8; ++g16) {                                      \
            const size_t row_ = (size_t)(rb_ + g16 * 16 + srow);                 \
            gll16(ssrc + row_ * 512 + s_half * 256 + dc_ * 32 + sdb * 8,         \
                  ld_ + g16 * 1024);                                             \
        }                                                                        \
    } while (0)

    STAGE(0, 0);
    __syncthreads();

    int buf = 0;
    for (int it = 0; it < KT_PER * 8; ++it) {
        const int kt = it >> 3, dc = it & 7;
        if (it + 1 < KT_PER * 8) STAGE(buf ^ 1, it + 1);

        const char* base = lds + buf * 32768;
        const char* zh = base, *zl = base + 8192, *ch = base + 16384, *cl = base + 24576;
        f16x8 Ah[4], Bh[4], T[4];
        #pragma unroll
        for (int f = 0; f < 4; ++f) Ah[f] = *(const f16x8*)(zh + offA[f]);
        #pragma unroll
        for (int f = 0; f < 4; ++f) Bh[f] = *(const f16x8*)(ch + offB[f]);
        #pragma unroll
        for (int fn = 0; fn < 4; ++fn)
            #pragma unroll
            for (int fk = 0; fk < 4; ++fk)
                acc1[fn][fk] = __builtin_amdgcn_mfma_f32_16x16x32_f16(
                    Ah[fn], Bh[fk], acc1[fn][fk], 0, 0, 0);
        #pragma unroll
        for (int f = 0; f < 4; ++f) T[f] = *(const f16x8*)(cl + offB[f]);
        #pragma unroll
        for (int fn = 0; fn < 4; ++fn)
            #pragma unroll
            for (int fk = 0; fk < 4; ++fk)
                acc2[fn][fk] = __builtin_amdgcn_mfma_f32_16x16x32_f16(
                    Ah[fn], T[fk], acc2[fn][fk], 0, 0, 0);
        #pragma unroll
        for (int f = 0; f < 4; ++f) T[f] = *(const f16x8*)(zl + offA[f]);
        #pragma unroll
        for (int fn = 0; fn < 4; ++fn)
            #pragma unroll
            for (int fk = 0; fk < 4; ++fk)
                acc2[fn][fk] = __builtin_amdgcn_mfma_f32_16x16x32_f16(
                    T[fn], Bh[fk], acc2[fn][fk], 0, 0, 0);

        if (dc == 7) {
            // g_true = (acc1 + acc2/2048)/4096; v = fl(A - 2*g_true) single-rounded
            const int k0 = kbase + kt * BK + wc * 64;
            float cn[4];
            #pragma unroll
            for (int fk = 0; fk < 4; ++fk) cn[fk] = cn2[k0 + fk * 16 + li];
            #pragma unroll
            for (int fn = 0; fn < 4; ++fn)
                #pragma unroll
                for (int fk = 0; fk < 4; ++fk) {
                    #pragma unroll
                    for (int r = 0; r < 4; ++r) {
                        const float t = fmaf(acc2[fn][fk][r], 4.8828125e-4f,
                                             acc1[fn][fk][r]);
                        const float A = zn[fn * 4 + r] + cn[fk];
                        const float v = fmaf(t, -4.8828125e-4f, A);
                        if (v < best[fn * 4 + r]) {
                            best[fn * 4 + r] = v;
                            bi[fn * 4 + r] = k0 + fk * 16 + li;
                        }
                    }
                    acc1[fn][fk] = f32x4{0.f, 0.f, 0.f, 0.f};
                    acc2[fn][fk] = f32x4{0.f, 0.f, 0.f, 0.f};
                }
        }
        __syncthreads();
        buf ^= 1;
    }

    // reduce across the 16 k-columns (li) per slot — butterfly, idx tie-break
    #pragma unroll
    for (int s = 0; s < 16; ++s) {
        float v = best[s]; int idx = bi[s];
        #pragma unroll
        for (int m = 1; m < 16; m <<= 1) {
            const float ov = __shfl_xor(v, m, 64);
            const int oi = __shfl_xor(idx, m, 64);
            if (ov < v || (ov == v && oi < idx)) { v = ov; idx = oi; }
        }
        best[s] = v; bi[s] = idx;
    }

    // cross-wave (wc) merge via LDS, then store per-ks partials
    float* mv = (float*)lds;
    int* mi = (int*)(lds + 512);
    if (wc == 1 && li == 0) {
        #pragma unroll
        for (int fn = 0; fn < 4; ++fn)
            #pragma unroll
            for (int r = 0; r < 4; ++r) {
                const int nl = wr * 64 + fn * 16 + 4 * g + r;
                mv[nl] = best[fn * 4 + r]; mi[nl] = bi[fn * 4 + r];
            }
    }
    __syncthreads();
    if (wc == 0 && li == 0) {
        #pragma unroll
        for (int fn = 0; fn < 4; ++fn)
            #pragma unroll
            for (int r = 0; r < 4; ++r) {
                const int nl = wr * 64 + fn * 16 + 4 * g + r;
                float v = best[fn * 4 + r]; int idx = bi[fn * 4 + r];
                const float ov = mv[nl]; const int oi = mi[nl];
                if (ov < v || (ov == v && oi < idx)) { v = ov; idx = oi; }
                const int n = nb + nl;
                pvals[(size_t)n * KSPLIT + ks] = v;
                pidx[(size_t)n * KSPLIT + ks] = idx;
            }
    }
    #undef STAGE
}

// ------------------------------------------------------- ksplit reduce ----
__global__ __launch_bounds__(256) void reduce_kernel(const float* __restrict__ pvals,
                                                     const int* __restrict__ pidx,
                                                     float* __restrict__ fidx) {
    const int n = blockIdx.x * 256 + threadIdx.x;
    float bv = 3.4e38f; int bidx = 0;
    #pragma unroll
    for (int s = 0; s < KSPLIT; ++s) {
        const float v = pvals[(size_t)n * KSPLIT + s];
        const int i = pidx[(size_t)n * KSPLIT + s];
        if (v < bv || (v == bv && i < bidx)) { bv = v; bidx = i; }
    }
    fidx[n] = (float)bidx;
}

// ------------------------------------------------------------- gather -----
__global__ __launch_bounds__(256) void gather_kernel(const float* __restrict__ emb,
                                                     const float* __restrict__ fidx,
                                                     float* __restrict__ zq) {
    const int tid = threadIdx.x;
    const int nb = blockIdx.x * 64;
    const int nl = tid & 63;
    const int dq = tid >> 6;
    const int b = nb >> 10, hw0 = nb & (HW - 1);
    const int k = (int)fidx[nb + nl];
    const float* er = emb + (size_t)k * D_DIM;
    float* ob = zq + (size_t)b * (D_DIM * HW) + hw0 + nl;
    #pragma unroll 8
    for (int dd = 0; dd < D_DIM; dd += 4) {
        const int d = dd + dq;
        ob[(size_t)d * HW] = er[d];
    }
}

// ------------------------------------------------------------- launch -----
extern "C" void kernel_launch(void* const* d_in, const int* in_sizes, int n_in,
                              void* d_out, int out_size, void* d_ws, size_t ws_size,
                              hipStream_t stream) {
    const float* z_e = (const float*)d_in[0];   // [16,256,32,32]
    const float* emb = (const float*)d_in[1];   // [8192,256]
    float* out = (float*)d_out;
    float* out_inp = out;                        // 4194304 floats
    float* out_zq  = out + 4194304;              // 4194304 floats
    float* out_idx = out + 8388608;              // 16384 floats

    // z3 fills the z_q output region exactly (gather overwrites it last);
    // c3 + norms + partials live in the inp region (memcpy overwrites last).
    f16*   z3    = (f16*)out_zq;                         // 16384*512 f16 = 16.8 MB
    f16*   c3    = (f16*)out_inp;                        // 8192*512 f16 = 8.4 MB
    float* zn2   = out_inp + 2097152;                    // 16384 floats
    float* cn2   = out_inp + 2113536;                    // 8192 floats
    float* pvals = out_inp + 2121728;                    // 131072 floats
    int*   pidx  = (int*)(out_inp + 2252800);            // 131072 ints

    zn2_kernel<<<N_TOT / 256, 256, 0, stream>>>(z_e, zn2);
    cn2_kernel<<<K_CODES / 256, 256, 0, stream>>>(emb, cn2);
    split_z_kernel<<<N_TOT / 256, 256, 0, stream>>>(z_e, z3);
    split_c_kernel<<<K_CODES / 256, 256, 0, stream>>>(emb, c3);
    vq_mfma_kernel<<<dim3(KSPLIT, N_TOT / BN), 256, 0, stream>>>(
        z3, c3, zn2, cn2, pvals, pidx);
    reduce_kernel<<<N_TOT / 256, 256, 0, stream>>>(pvals, pidx, out_idx);
    gather_kernel<<<N_TOT / 64, 256, 0, stream>>>(emb, out_idx, out_zq);
    hipMemcpyAsync(out_inp, z_e, (size_t)N_TOT * D_DIM * sizeof(float),
                   hipMemcpyDeviceToDevice, stream);
}